// Round 1
// baseline (2129.685 us; speedup 1.0000x reference)
//
#include <hip/hip_runtime.h>
#include <hip/hip_cooperative_groups.h>

namespace cg = cooperative_groups;

// Problem constants
#define BB 16
#define NN 512
#define HH 128

// ---------------------------------------------------------------- embed ----
// x[b,n,h] = points[b,n,0]*W_emb[0,h] + points[b,n,1]*W_emb[1,h] + b_emb[h]
__global__ __launch_bounds__(256) void embed_kernel(
    const float* __restrict__ pts, const float* __restrict__ Wemb,
    const float* __restrict__ bemb, float* __restrict__ x)
{
  int idx = blockIdx.x * 256 + threadIdx.x;   // 0 .. B*N*H
  int h  = idx & (HH - 1);
  int bn = idx >> 7;
  float p0 = pts[bn * 2 + 0], p1 = pts[bn * 2 + 1];
  x[idx] = fmaf(p0, Wemb[h], fmaf(p1, Wemb[HH + h], bemb[h]));
}

// ----------------------------------------------------------------- GEMM ----
// C[b] = op(A[b] @ B[b or shared] + bias)
// MODE 0: plain (bmm).  MODE 1: +bias, relu (B shared weights).
// MODE 2: logits epilogue (diag mask, 10*tanh, gumbel, /T) -> writes y.
// EXPA: A element = exp(-raw) (adjacency fused from distances).
// TRANSB: B[k][n] = Braw[n][k] (for x @ x^T).
constexpr int BMt = 64, BNt = 64, BKt = 32;

template <int MODE, bool EXPA, bool TRANSB, int Mdim, int Ndim, int Kdim>
__global__ __launch_bounds__(256) void gemm_kernel(
    const float* __restrict__ Ag, const float* __restrict__ Bg,
    const float* __restrict__ bias, const float* __restrict__ noise,
    float* __restrict__ Cg)
{
  constexpr int TMn = Mdim / BMt, TNn = Ndim / BNt;
  const int bid = blockIdx.x;
  const int tn  = bid % TNn;
  const int tmi = (bid / TNn) % TMn;
  const int b   = bid / (TNn * TMn);
  const int tid = threadIdx.x;
  const int row0 = tmi * BMt, col0 = tn * BNt;

  __shared__ float Al[BKt][BMt + 4];
  __shared__ float Bl[BKt][BNt + 4];

  const float* Ab = Ag + (size_t)b * Mdim * Kdim;
  const size_t bstrideB = (MODE == 1) ? (size_t)0 : (size_t)Kdim * Ndim; // trans: N*K == K*N
  const float* Bb = Bg + (size_t)b * bstrideB;

  const int rowr = (tid >> 4) * 4;   // 0..60
  const int colr = (tid & 15) * 4;   // 0..60

  float acc[4][4] = {};

  for (int k0 = 0; k0 < Kdim; k0 += BKt) {
    // ---- stage A (optionally exp(-a)) : Al[k][m]
    {
      int r = tid >> 3, kq = (tid & 7) * 4;
      #pragma unroll
      for (int rr = 0; rr < BMt; rr += 32) {
        float4 v = *reinterpret_cast<const float4*>(
            &Ab[(size_t)(row0 + r + rr) * Kdim + k0 + kq]);
        if (EXPA) {
          v.x = __expf(-v.x); v.y = __expf(-v.y);
          v.z = __expf(-v.z); v.w = __expf(-v.w);
        }
        Al[kq + 0][r + rr] = v.x; Al[kq + 1][r + rr] = v.y;
        Al[kq + 2][r + rr] = v.z; Al[kq + 3][r + rr] = v.w;
      }
    }
    // ---- stage B : Bl[k][n]
    if (!TRANSB) {
      int kk = tid >> 4, nc = (tid & 15) * 4;
      #pragma unroll
      for (int kr = 0; kr < BKt; kr += 16) {
        float4 v = *reinterpret_cast<const float4*>(
            &Bb[(size_t)(k0 + kk + kr) * Ndim + col0 + nc]);
        *reinterpret_cast<float4*>(&Bl[kk + kr][nc]) = v;
      }
    } else {
      int n = tid >> 3, kq = (tid & 7) * 4;
      #pragma unroll
      for (int nr = 0; nr < BNt; nr += 32) {
        float4 v = *reinterpret_cast<const float4*>(
            &Bb[(size_t)(col0 + n + nr) * Kdim + k0 + kq]);
        Bl[kq + 0][n + nr] = v.x; Bl[kq + 1][n + nr] = v.y;
        Bl[kq + 2][n + nr] = v.z; Bl[kq + 3][n + nr] = v.w;
      }
    }
    __syncthreads();

    #pragma unroll
    for (int kk = 0; kk < BKt; ++kk) {
      const float4 a4 = *reinterpret_cast<const float4*>(&Al[kk][rowr]);
      const float4 b4 = *reinterpret_cast<const float4*>(&Bl[kk][colr]);
      const float av[4] = {a4.x, a4.y, a4.z, a4.w};
      const float bw[4] = {b4.x, b4.y, b4.z, b4.w};
      #pragma unroll
      for (int i = 0; i < 4; ++i)
        #pragma unroll
        for (int j = 0; j < 4; ++j)
          acc[i][j] = fmaf(av[i], bw[j], acc[i][j]);
    }
    __syncthreads();
  }

  // ---- epilogue
  float* Cb = Cg + (size_t)b * Mdim * Ndim;
  #pragma unroll
  for (int i = 0; i < 4; ++i) {
    const int gi = row0 + rowr + i;
    float vals[4];
    #pragma unroll
    for (int j = 0; j < 4; ++j) {
      const int gj = col0 + colr + j;
      float s = acc[i][j];
      if (MODE == 1) { s += bias[gj]; s = fmaxf(s, 0.0f); }
      if (MODE == 2) {
        if (gi == gj) s -= 1e9f;
        float th = 1.0f - 2.0f / (__expf(2.0f * s) + 1.0f);   // tanh(s)
        float u  = noise[(size_t)b * Mdim * Ndim + (size_t)gi * Ndim + gj];
        float eps = -__logf(-__logf(u));                       // Gumbel
        s = (10.0f * th + 0.01f * eps) * (1.0f / 3.0f);
      }
      vals[j] = s;
    }
    *reinterpret_cast<float4*>(&Cb[(size_t)gi * Ndim + col0 + colr]) =
        make_float4(vals[0], vals[1], vals[2], vals[3]);
  }
}

// ----------------------------------------------------- row max + exp -------
// In place on y (d_out): P0 = exp(y - rowmax).  No division — the softmax
// row-sum is folded into the Sinkhorn r0.
__global__ __launch_bounds__(256) void rowexp_kernel(float* __restrict__ y)
{
  const int row = blockIdx.x;                 // 0 .. B*N
  float* p = y + (size_t)row * NN;
  const int t = threadIdx.x;
  float v0 = p[t], v1 = p[t + 256];
  float m = fmaxf(v0, v1);
  #pragma unroll
  for (int off = 32; off >= 1; off >>= 1) m = fmaxf(m, __shfl_xor(m, off));
  __shared__ float wm[4];
  if ((t & 63) == 0) wm[t >> 6] = m;
  __syncthreads();
  m = fmaxf(fmaxf(wm[0], wm[1]), fmaxf(wm[2], wm[3]));
  p[t]       = __expf(v0 - m);
  p[t + 256] = __expf(v1 - m);
}

// ----------------------------------------------------------- Sinkhorn ------
// Factorized: P_final = diag(r) P0 diag(c);
//   r0 = 1/rowsum(P0) (== softmax), then 60x { c = 1/(P0^T r); r = 1/(P0 c) }.
// 256 blocks = 16 per batch x 32 rows; slab of P0 lives in LDS (f32, stride
// 513 to avoid 32-way bank conflicts on row-wise reads). Only the partial
// column sums cross blocks -> ONE grid.sync per iteration, double-buffered.
__global__ __launch_bounds__(256) void sinkhorn_kernel(
    const float* __restrict__ P0, float* __restrict__ pu, float* __restrict__ out)
{
  cg::grid_group grid = cg::this_grid();

  __shared__ float Pl[32][513];
  __shared__ float cl[512];
  __shared__ float rl[32];
  __shared__ float red[8][32];

  const int bid = blockIdx.x;
  const int b = bid >> 4, s = bid & 15;
  const int tid = threadIdx.x;
  const float* Pb = P0 + ((size_t)b * NN + s * 32) * NN;

  // stage 32x512 slab
  for (int f = tid; f < 32 * 128; f += 256) {
    int r = f >> 7, c4 = (f & 127) * 4;
    float4 v = *reinterpret_cast<const float4*>(&Pb[(size_t)r * NN + c4]);
    Pl[r][c4 + 0] = v.x; Pl[r][c4 + 1] = v.y;
    Pl[r][c4 + 2] = v.z; Pl[r][c4 + 3] = v.w;
  }
  cl[tid] = 1.0f; cl[tid + 256] = 1.0f;
  __syncthreads();

  auto row_update = [&]() {  // r_i = 1 / sum_j Pl[i][j] * cl[j]
    const int i = tid & 31, ch = tid >> 5;
    const int j0 = ch * 64;
    float p = 0.0f;
    #pragma unroll 8
    for (int q = 0; q < 64; ++q) p = fmaf(Pl[i][j0 + q], cl[j0 + q], p);
    red[ch][i] = p;
    __syncthreads();
    if (tid < 32) {
      float v = 0.0f;
      #pragma unroll
      for (int q = 0; q < 8; ++q) v += red[q][tid];
      rl[tid] = 1.0f / v;
    }
    __syncthreads();
  };
  row_update();  // r0 = softmax row normalization

  for (int it = 0; it < 60; ++it) {
    float* pw = pu + (((size_t)(it & 1) * BB + b) * 16 + s) * NN;
    // phase A: partial column sums over this block's 32 rows
    {
      float u0 = 0.0f, u1 = 0.0f;
      #pragma unroll 8
      for (int i2 = 0; i2 < 32; ++i2) {
        const float rv = rl[i2];
        u0 = fmaf(Pl[i2][tid],       rv, u0);
        u1 = fmaf(Pl[i2][tid + 256], rv, u1);
      }
      pw[tid] = u0; pw[tid + 256] = u1;
    }
    grid.sync();
    // phase B: c = 1/colsum ; then local row matvec -> r
    {
      const float* pr = pu + (((size_t)(it & 1) * BB + b) * 16) * NN;
      float t0 = 0.0f, t1 = 0.0f;
      #pragma unroll
      for (int sp = 0; sp < 16; ++sp) {
        t0 += pr[sp * NN + tid];
        t1 += pr[sp * NN + tid + 256];
      }
      cl[tid] = 1.0f / t0; cl[tid + 256] = 1.0f / t1;
    }
    __syncthreads();
    row_update();
  }

  // final: out = r_i * P0_ij * c_j   (reads LDS only; safe to overwrite P0)
  float* Ob = out + ((size_t)b * NN + s * 32) * NN;
  for (int i = 0; i < 32; ++i) {
    const float rv = rl[i];
    Ob[(size_t)i * NN + tid]       = rv * Pl[i][tid]       * cl[tid];
    Ob[(size_t)i * NN + tid + 256] = rv * Pl[i][tid + 256] * cl[tid + 256];
  }
}

// ------------------------------------------------------------- launch ------
extern "C" void kernel_launch(void* const* d_in, const int* in_sizes, int n_in,
                              void* d_out, int out_size, void* d_ws, size_t ws_size,
                              hipStream_t stream)
{
  const float* points = (const float*)d_in[0];
  const float* dist   = (const float*)d_in[1];
  const float* noise  = (const float*)d_in[2];
  const float* Wemb   = (const float*)d_in[3];
  const float* bemb   = (const float*)d_in[4];
  const float* W1 = (const float*)d_in[5]; const float* b1 = (const float*)d_in[6];
  const float* W2 = (const float*)d_in[7]; const float* b2 = (const float*)d_in[8];
  const float* W3 = (const float*)d_in[9]; const float* b3 = (const float*)d_in[10];
  float* out = (float*)d_out;

  char* ws = (char*)d_ws;
  float* xa = (float*)ws;                        // B*N*H f32 = 4 MB
  float* nb = (float*)(ws + (4u << 20));         // B*N*H f32 = 4 MB
  float* pu = (float*)(ws + (8u << 20));         // 2*16*16*512 f32 = 1 MB

  // embed
  embed_kernel<<<(BB * NN * HH) / 256, 256, 0, stream>>>(points, Wemb, bemb, xa);

  // 3 GCN layers: nb = exp(-dist) @ x ; x = relu(nb @ W + b)
  constexpr int GRID_BMM = BB * (NN / BMt) * (HH / BNt);   // 256
  gemm_kernel<0, true,  false, NN, HH, NN><<<GRID_BMM, 256, 0, stream>>>(dist, xa, nullptr, nullptr, nb);
  gemm_kernel<1, false, false, NN, HH, HH><<<GRID_BMM, 256, 0, stream>>>(nb, W1, b1, nullptr, xa);
  gemm_kernel<0, true,  false, NN, HH, NN><<<GRID_BMM, 256, 0, stream>>>(dist, xa, nullptr, nullptr, nb);
  gemm_kernel<1, false, false, NN, HH, HH><<<GRID_BMM, 256, 0, stream>>>(nb, W2, b2, nullptr, xa);
  gemm_kernel<0, true,  false, NN, HH, NN><<<GRID_BMM, 256, 0, stream>>>(dist, xa, nullptr, nullptr, nb);
  gemm_kernel<1, false, false, NN, HH, HH><<<GRID_BMM, 256, 0, stream>>>(nb, W3, b3, nullptr, xa);

  // logits -> y (in d_out), fused mask/tanh/gumbel/T
  constexpr int GRID_LOG = BB * (NN / BMt) * (NN / BNt);   // 1024
  gemm_kernel<2, false, true, NN, NN, HH><<<GRID_LOG, 256, 0, stream>>>(xa, xa, nullptr, noise, out);

  // P0 = exp(y - rowmax)  (in place)
  rowexp_kernel<<<BB * NN, 256, 0, stream>>>(out);

  // Sinkhorn (cooperative, 60 grid syncs), final P overwrites d_out
  const float* P0c = out; float* puP = pu; float* outP = out;
  void* args[] = {(void*)&P0c, (void*)&puP, (void*)&outP};
  hipLaunchCooperativeKernel(reinterpret_cast<void*>(sinkhorn_kernel),
                             dim3(256), dim3(256), args, 0, stream);
}

// Round 2
// 1704.114 us; speedup vs baseline: 1.2497x; 1.2497x over previous
//
#include <hip/hip_runtime.h>
#include <hip/hip_cooperative_groups.h>

namespace cg = cooperative_groups;

// Problem constants
#define BB 16
#define NN 512
#define HH 128

#define SCOPE_AGENT __HIP_MEMORY_SCOPE_AGENT

// ---------------------------------------------------------------- embed ----
__global__ __launch_bounds__(256) void embed_kernel(
    const float* __restrict__ pts, const float* __restrict__ Wemb,
    const float* __restrict__ bemb, float* __restrict__ x)
{
  int idx = blockIdx.x * 256 + threadIdx.x;   // 0 .. B*N*H
  int h  = idx & (HH - 1);
  int bn = idx >> 7;
  float p0 = pts[bn * 2 + 0], p1 = pts[bn * 2 + 1];
  x[idx] = fmaf(p0, Wemb[h], fmaf(p1, Wemb[HH + h], bemb[h]));
}

// ----------------------------------------------------------------- GEMM ----
// MODE 0: plain (bmm).  MODE 1: +bias, relu (B shared weights).
// MODE 2: logits epilogue (diag mask, 10*tanh, gumbel, /T).
// EXPA: A element = exp(-raw).  TRANSB: B[k][n] = Braw[n][k].
constexpr int BMt = 64, BNt = 64, BKt = 32;

template <int MODE, bool EXPA, bool TRANSB, int Mdim, int Ndim, int Kdim>
__global__ __launch_bounds__(256) void gemm_kernel(
    const float* __restrict__ Ag, const float* __restrict__ Bg,
    const float* __restrict__ bias, const float* __restrict__ noise,
    float* __restrict__ Cg)
{
  constexpr int TMn = Mdim / BMt, TNn = Ndim / BNt;
  const int bid = blockIdx.x;
  const int tn  = bid % TNn;
  const int tmi = (bid / TNn) % TMn;
  const int b   = bid / (TNn * TMn);
  const int tid = threadIdx.x;
  const int row0 = tmi * BMt, col0 = tn * BNt;

  __shared__ float Al[BKt][BMt + 4];
  __shared__ float Bl[BKt][BNt + 4];

  const float* Ab = Ag + (size_t)b * Mdim * Kdim;
  const size_t bstrideB = (MODE == 1) ? (size_t)0 : (size_t)Kdim * Ndim;
  const float* Bb = Bg + (size_t)b * bstrideB;

  const int rowr = (tid >> 4) * 4;
  const int colr = (tid & 15) * 4;

  float acc[4][4] = {};

  for (int k0 = 0; k0 < Kdim; k0 += BKt) {
    {
      int r = tid >> 3, kq = (tid & 7) * 4;
      #pragma unroll
      for (int rr = 0; rr < BMt; rr += 32) {
        float4 v = *reinterpret_cast<const float4*>(
            &Ab[(size_t)(row0 + r + rr) * Kdim + k0 + kq]);
        if (EXPA) {
          v.x = __expf(-v.x); v.y = __expf(-v.y);
          v.z = __expf(-v.z); v.w = __expf(-v.w);
        }
        Al[kq + 0][r + rr] = v.x; Al[kq + 1][r + rr] = v.y;
        Al[kq + 2][r + rr] = v.z; Al[kq + 3][r + rr] = v.w;
      }
    }
    if (!TRANSB) {
      int kk = tid >> 4, nc = (tid & 15) * 4;
      #pragma unroll
      for (int kr = 0; kr < BKt; kr += 16) {
        float4 v = *reinterpret_cast<const float4*>(
            &Bb[(size_t)(k0 + kk + kr) * Ndim + col0 + nc]);
        *reinterpret_cast<float4*>(&Bl[kk + kr][nc]) = v;
      }
    } else {
      int n = tid >> 3, kq = (tid & 7) * 4;
      #pragma unroll
      for (int nr = 0; nr < BNt; nr += 32) {
        float4 v = *reinterpret_cast<const float4*>(
            &Bb[(size_t)(col0 + n + nr) * Kdim + k0 + kq]);
        Bl[kq + 0][n + nr] = v.x; Bl[kq + 1][n + nr] = v.y;
        Bl[kq + 2][n + nr] = v.z; Bl[kq + 3][n + nr] = v.w;
      }
    }
    __syncthreads();

    #pragma unroll
    for (int kk = 0; kk < BKt; ++kk) {
      const float4 a4 = *reinterpret_cast<const float4*>(&Al[kk][rowr]);
      const float4 b4 = *reinterpret_cast<const float4*>(&Bl[kk][colr]);
      const float av[4] = {a4.x, a4.y, a4.z, a4.w};
      const float bw[4] = {b4.x, b4.y, b4.z, b4.w};
      #pragma unroll
      for (int i = 0; i < 4; ++i)
        #pragma unroll
        for (int j = 0; j < 4; ++j)
          acc[i][j] = fmaf(av[i], bw[j], acc[i][j]);
    }
    __syncthreads();
  }

  float* Cb = Cg + (size_t)b * Mdim * Ndim;
  #pragma unroll
  for (int i = 0; i < 4; ++i) {
    const int gi = row0 + rowr + i;
    float vals[4];
    #pragma unroll
    for (int j = 0; j < 4; ++j) {
      const int gj = col0 + colr + j;
      float s = acc[i][j];
      if (MODE == 1) { s += bias[gj]; s = fmaxf(s, 0.0f); }
      if (MODE == 2) {
        if (gi == gj) s -= 1e9f;
        float th = 1.0f - 2.0f / (__expf(2.0f * s) + 1.0f);   // tanh(s)
        float u  = noise[(size_t)b * Mdim * Ndim + (size_t)gi * Ndim + gj];
        float eps = -__logf(-__logf(u));                       // Gumbel
        s = (10.0f * th + 0.01f * eps) * (1.0f / 3.0f);
      }
      vals[j] = s;
    }
    *reinterpret_cast<float4*>(&Cb[(size_t)gi * Ndim + col0 + colr]) =
        make_float4(vals[0], vals[1], vals[2], vals[3]);
  }
}

// ----------------------------------------------------- row max + exp -------
__global__ __launch_bounds__(256) void rowexp_kernel(float* __restrict__ y)
{
  const int row = blockIdx.x;                 // 0 .. B*N
  float* p = y + (size_t)row * NN;
  const int t = threadIdx.x;
  float v0 = p[t], v1 = p[t + 256];
  float m = fmaxf(v0, v1);
  #pragma unroll
  for (int off = 32; off >= 1; off >>= 1) m = fmaxf(m, __shfl_xor(m, off));
  __shared__ float wm[4];
  if ((t & 63) == 0) wm[t >> 6] = m;
  __syncthreads();
  m = fmaxf(fmaxf(wm[0], wm[1]), fmaxf(wm[2], wm[3]));
  p[t]       = __expf(v0 - m);
  p[t + 256] = __expf(v1 - m);
}

// ----------------------------------------------------------- Sinkhorn ------
// Factorized: P_final = diag(r) P0 diag(c).
// 256 blocks = 16 per batch x 32 rows; P0 slab in LDS (stride 513).
// Cross-block exchange (512 partial col-sums per batch) via agent-scope
// (L2-bypassing, IF$-coherent) atomic loads/stores; per-batch hand-rolled
// barrier: monotonic counter, release add + relaxed poll + acquire load.
// One barrier per iteration, partials double-buffered.
__global__ __launch_bounds__(256) void sinkhorn_kernel(
    const float* __restrict__ P0, float* __restrict__ pu,
    unsigned int* __restrict__ bar, float* __restrict__ out)
{
  __shared__ float Pl[32][513];
  __shared__ float cl[512];
  __shared__ float rl[32];
  __shared__ float red[8][32];

  const int bid = blockIdx.x;
  const int b = bid >> 4, s = bid & 15;
  const int tid = threadIdx.x;
  const float* Pb = P0 + ((size_t)b * NN + s * 32) * NN;

  // stage 32x512 slab
  for (int f = tid; f < 32 * 128; f += 256) {
    int r = f >> 7, c4 = (f & 127) * 4;
    float4 v = *reinterpret_cast<const float4*>(&Pb[(size_t)r * NN + c4]);
    Pl[r][c4 + 0] = v.x; Pl[r][c4 + 1] = v.y;
    Pl[r][c4 + 2] = v.z; Pl[r][c4 + 3] = v.w;
  }
  cl[tid] = 1.0f; cl[tid + 256] = 1.0f;
  __syncthreads();

  auto row_update = [&]() {  // r_i = 1 / sum_j Pl[i][j] * cl[j]
    const int i = tid & 31, ch = tid >> 5;
    const int j0 = ch * 64;
    float p = 0.0f;
    #pragma unroll 8
    for (int q = 0; q < 64; ++q) p = fmaf(Pl[i][j0 + q], cl[j0 + q], p);
    red[ch][i] = p;
    __syncthreads();
    if (tid < 32) {
      float v = 0.0f;
      #pragma unroll
      for (int q = 0; q < 8; ++q) v += red[q][tid];
      rl[tid] = 1.0f / v;
    }
    __syncthreads();
  };
  row_update();  // r0 = softmax row normalization (folded)

  for (int it = 0; it < 60; ++it) {
    // phase A: partial column sums over this block's 32 rows -> publish
    float* pw = pu + (((size_t)(it & 1) * BB + b) * 16 + s) * NN;
    {
      float u0 = 0.0f, u1 = 0.0f;
      #pragma unroll 8
      for (int i2 = 0; i2 < 32; ++i2) {
        const float rv = rl[i2];
        u0 = fmaf(Pl[i2][tid],       rv, u0);
        u1 = fmaf(Pl[i2][tid + 256], rv, u1);
      }
      __hip_atomic_store(&pw[tid],       u0, __ATOMIC_RELAXED, SCOPE_AGENT);
      __hip_atomic_store(&pw[tid + 256], u1, __ATOMIC_RELAXED, SCOPE_AGENT);
    }
    __syncthreads();  // compiler drains vmcnt(0) per wave before s_barrier

    // per-batch barrier (16 blocks), monotonic counter
    if (tid == 0) {
      __hip_atomic_fetch_add(&bar[b], 1u, __ATOMIC_RELEASE, SCOPE_AGENT);
      const unsigned int target = 16u * (unsigned int)(it + 1);
      while (__hip_atomic_load(&bar[b], __ATOMIC_RELAXED, SCOPE_AGENT) < target)
        __builtin_amdgcn_s_sleep(2);
      (void)__hip_atomic_load(&bar[b], __ATOMIC_ACQUIRE, SCOPE_AGENT);
    }
    __syncthreads();

    // phase B: c = 1/colsum ; then local row matvec -> r
    {
      const float* pr = pu + (((size_t)(it & 1) * BB + b) * 16) * NN;
      float t0 = 0.0f, t1 = 0.0f;
      #pragma unroll
      for (int sp = 0; sp < 16; ++sp) {
        t0 += __hip_atomic_load(&pr[sp * NN + tid],       __ATOMIC_RELAXED, SCOPE_AGENT);
        t1 += __hip_atomic_load(&pr[sp * NN + tid + 256], __ATOMIC_RELAXED, SCOPE_AGENT);
      }
      cl[tid] = 1.0f / t0; cl[tid + 256] = 1.0f / t1;
    }
    __syncthreads();
    row_update();
  }

  // final: out = r_i * P0_ij * c_j   (reads LDS only)
  float* Ob = out + ((size_t)b * NN + s * 32) * NN;
  for (int i = 0; i < 32; ++i) {
    const float rv = rl[i];
    Ob[(size_t)i * NN + tid]       = rv * Pl[i][tid]       * cl[tid];
    Ob[(size_t)i * NN + tid + 256] = rv * Pl[i][tid + 256] * cl[tid + 256];
  }
}

// ------------------------------------------------------------- launch ------
extern "C" void kernel_launch(void* const* d_in, const int* in_sizes, int n_in,
                              void* d_out, int out_size, void* d_ws, size_t ws_size,
                              hipStream_t stream)
{
  const float* points = (const float*)d_in[0];
  const float* dist   = (const float*)d_in[1];
  const float* noise  = (const float*)d_in[2];
  const float* Wemb   = (const float*)d_in[3];
  const float* bemb   = (const float*)d_in[4];
  const float* W1 = (const float*)d_in[5]; const float* b1 = (const float*)d_in[6];
  const float* W2 = (const float*)d_in[7]; const float* b2 = (const float*)d_in[8];
  const float* W3 = (const float*)d_in[9]; const float* b3 = (const float*)d_in[10];
  float* out = (float*)d_out;

  char* ws = (char*)d_ws;
  float* xa = (float*)ws;                              // B*N*H f32 = 4 MB
  float* nb = (float*)(ws + (4u << 20));               // B*N*H f32 = 4 MB
  float* pu = (float*)(ws + (8u << 20));               // 2*16*16*512 f32 = 1 MB
  unsigned int* bar = (unsigned int*)(ws + (9u << 20)); // 16 counters

  hipMemsetAsync(bar, 0, BB * sizeof(unsigned int), stream);

  // embed
  embed_kernel<<<(BB * NN * HH) / 256, 256, 0, stream>>>(points, Wemb, bemb, xa);

  // 3 GCN layers: nb = exp(-dist) @ x ; x = relu(nb @ W + b)
  constexpr int GRID_BMM = BB * (NN / BMt) * (HH / BNt);   // 256
  gemm_kernel<0, true,  false, NN, HH, NN><<<GRID_BMM, 256, 0, stream>>>(dist, xa, nullptr, nullptr, nb);
  gemm_kernel<1, false, false, NN, HH, HH><<<GRID_BMM, 256, 0, stream>>>(nb, W1, b1, nullptr, xa);
  gemm_kernel<0, true,  false, NN, HH, NN><<<GRID_BMM, 256, 0, stream>>>(dist, xa, nullptr, nullptr, nb);
  gemm_kernel<1, false, false, NN, HH, HH><<<GRID_BMM, 256, 0, stream>>>(nb, W2, b2, nullptr, xa);
  gemm_kernel<0, true,  false, NN, HH, NN><<<GRID_BMM, 256, 0, stream>>>(dist, xa, nullptr, nullptr, nb);
  gemm_kernel<1, false, false, NN, HH, HH><<<GRID_BMM, 256, 0, stream>>>(nb, W3, b3, nullptr, xa);

  // logits -> y (in d_out), fused mask/tanh/gumbel/T
  constexpr int GRID_LOG = BB * (NN / BMt) * (NN / BNt);   // 1024
  gemm_kernel<2, false, true, NN, NN, HH><<<GRID_LOG, 256, 0, stream>>>(xa, xa, nullptr, noise, out);

  // P0 = exp(y - rowmax)  (in place)
  rowexp_kernel<<<BB * NN, 256, 0, stream>>>(out);

  // Sinkhorn: cooperative launch only for co-residency; sync is hand-rolled.
  const float* P0c = out; float* puP = pu; unsigned int* barP = bar; float* outP = out;
  void* args[] = {(void*)&P0c, (void*)&puP, (void*)&barP, (void*)&outP};
  hipLaunchCooperativeKernel(reinterpret_cast<void*>(sinkhorn_kernel),
                             dim3(256), dim3(256), args, 0, stream);
}

// Round 3
// 361.619 us; speedup vs baseline: 5.8893x; 4.7125x over previous
//
#include <hip/hip_runtime.h>

// Problem constants
#define BB 16
#define NN 512
#define HH 128

#define SCOPE_AGENT __HIP_MEMORY_SCOPE_AGENT

// ---------------------------------------------------------------- embed ----
__global__ __launch_bounds__(256) void embed_kernel(
    const float* __restrict__ pts, const float* __restrict__ Wemb,
    const float* __restrict__ bemb, float* __restrict__ x)
{
  int idx = blockIdx.x * 256 + threadIdx.x;   // 0 .. B*N*H
  int h  = idx & (HH - 1);
  int bn = idx >> 7;
  float p0 = pts[bn * 2 + 0], p1 = pts[bn * 2 + 1];
  x[idx] = fmaf(p0, Wemb[h], fmaf(p1, Wemb[HH + h], bemb[h]));
}

// ----------------------------------------------------------------- GEMM ----
// MODE 0: plain (bmm).  MODE 1: +bias, relu (B shared weights).
// MODE 2: logits epilogue (diag mask, 10*tanh, gumbel, /T).
// EXPA: A element = exp(-raw).  TRANSB: B[k][n] = Braw[n][k].
constexpr int BMt = 64, BNt = 64, BKt = 32;

template <int MODE, bool EXPA, bool TRANSB, int Mdim, int Ndim, int Kdim>
__global__ __launch_bounds__(256) void gemm_kernel(
    const float* __restrict__ Ag, const float* __restrict__ Bg,
    const float* __restrict__ bias, const float* __restrict__ noise,
    float* __restrict__ Cg)
{
  constexpr int TMn = Mdim / BMt, TNn = Ndim / BNt;
  const int bid = blockIdx.x;
  const int tn  = bid % TNn;
  const int tmi = (bid / TNn) % TMn;
  const int b   = bid / (TNn * TMn);
  const int tid = threadIdx.x;
  const int row0 = tmi * BMt, col0 = tn * BNt;

  __shared__ float Al[BKt][BMt + 4];
  __shared__ float Bl[BKt][BNt + 4];

  const float* Ab = Ag + (size_t)b * Mdim * Kdim;
  const size_t bstrideB = (MODE == 1) ? (size_t)0 : (size_t)Kdim * Ndim;
  const float* Bb = Bg + (size_t)b * bstrideB;

  const int rowr = (tid >> 4) * 4;
  const int colr = (tid & 15) * 4;

  float acc[4][4] = {};

  for (int k0 = 0; k0 < Kdim; k0 += BKt) {
    {
      int r = tid >> 3, kq = (tid & 7) * 4;
      #pragma unroll
      for (int rr = 0; rr < BMt; rr += 32) {
        float4 v = *reinterpret_cast<const float4*>(
            &Ab[(size_t)(row0 + r + rr) * Kdim + k0 + kq]);
        if (EXPA) {
          v.x = __expf(-v.x); v.y = __expf(-v.y);
          v.z = __expf(-v.z); v.w = __expf(-v.w);
        }
        Al[kq + 0][r + rr] = v.x; Al[kq + 1][r + rr] = v.y;
        Al[kq + 2][r + rr] = v.z; Al[kq + 3][r + rr] = v.w;
      }
    }
    if (!TRANSB) {
      int kk = tid >> 4, nc = (tid & 15) * 4;
      #pragma unroll
      for (int kr = 0; kr < BKt; kr += 16) {
        float4 v = *reinterpret_cast<const float4*>(
            &Bb[(size_t)(k0 + kk + kr) * Ndim + col0 + nc]);
        *reinterpret_cast<float4*>(&Bl[kk + kr][nc]) = v;
      }
    } else {
      int n = tid >> 3, kq = (tid & 7) * 4;
      #pragma unroll
      for (int nr = 0; nr < BNt; nr += 32) {
        float4 v = *reinterpret_cast<const float4*>(
            &Bb[(size_t)(col0 + n + nr) * Kdim + k0 + kq]);
        Bl[kq + 0][n + nr] = v.x; Bl[kq + 1][n + nr] = v.y;
        Bl[kq + 2][n + nr] = v.z; Bl[kq + 3][n + nr] = v.w;
      }
    }
    __syncthreads();

    #pragma unroll
    for (int kk = 0; kk < BKt; ++kk) {
      const float4 a4 = *reinterpret_cast<const float4*>(&Al[kk][rowr]);
      const float4 b4 = *reinterpret_cast<const float4*>(&Bl[kk][colr]);
      const float av[4] = {a4.x, a4.y, a4.z, a4.w};
      const float bw[4] = {b4.x, b4.y, b4.z, b4.w};
      #pragma unroll
      for (int i = 0; i < 4; ++i)
        #pragma unroll
        for (int j = 0; j < 4; ++j)
          acc[i][j] = fmaf(av[i], bw[j], acc[i][j]);
    }
    __syncthreads();
  }

  float* Cb = Cg + (size_t)b * Mdim * Ndim;
  #pragma unroll
  for (int i = 0; i < 4; ++i) {
    const int gi = row0 + rowr + i;
    float vals[4];
    #pragma unroll
    for (int j = 0; j < 4; ++j) {
      const int gj = col0 + colr + j;
      float s = acc[i][j];
      if (MODE == 1) { s += bias[gj]; s = fmaxf(s, 0.0f); }
      if (MODE == 2) {
        if (gi == gj) s -= 1e9f;
        float th = 1.0f - 2.0f / (__expf(2.0f * s) + 1.0f);   // tanh(s)
        float u  = noise[(size_t)b * Mdim * Ndim + (size_t)gi * Ndim + gj];
        float eps = -__logf(-__logf(u));                       // Gumbel
        s = (10.0f * th + 0.01f * eps) * (1.0f / 3.0f);
      }
      vals[j] = s;
    }
    *reinterpret_cast<float4*>(&Cb[(size_t)gi * Ndim + col0 + colr]) =
        make_float4(vals[0], vals[1], vals[2], vals[3]);
  }
}

// ----------------------------------------------------- row max + exp -------
__global__ __launch_bounds__(256) void rowexp_kernel(float* __restrict__ y)
{
  const int row = blockIdx.x;                 // 0 .. B*N
  float* p = y + (size_t)row * NN;
  const int t = threadIdx.x;
  float v0 = p[t], v1 = p[t + 256];
  float m = fmaxf(v0, v1);
  #pragma unroll
  for (int off = 32; off >= 1; off >>= 1) m = fmaxf(m, __shfl_xor(m, off));
  __shared__ float wm[4];
  if ((t & 63) == 0) wm[t >> 6] = m;
  __syncthreads();
  m = fmaxf(fmaxf(wm[0], wm[1]), fmaxf(wm[2], wm[3]));
  p[t]       = __expf(v0 - m);
  p[t + 256] = __expf(v1 - m);
}

// ----------------------------------------------------------- Sinkhorn ------
// Factorized: P_final = diag(r) P0 diag(c).
// 256 blocks = 16 per batch x 32 rows; P0 slab in LDS (stride 513).
// Cross-block exchange via agent-scope (sc0 sc1, L2-bypassing) relaxed
// atomics ONLY — no acquire/release (avoids buffer_wbl2/buffer_inv L2
// maintenance each iteration). Ordering: __syncthreads() drains vmcnt(0)
// per wave, so data is at the coherence point before the flag store.
// Barrier: distributed per-block monotonic flags, 256B-padded (one line
// each); 16 lanes poll the batch's 16 flags in parallel.
__global__ __launch_bounds__(256) void sinkhorn_kernel(
    const float* __restrict__ P0, float* __restrict__ pu,
    unsigned int* __restrict__ flags, float* __restrict__ out)
{
  __shared__ float Pl[32][513];
  __shared__ float cl[512];
  __shared__ float rl[32];
  __shared__ float red[8][32];

  const int bid = blockIdx.x;
  const int b = bid >> 4, s = bid & 15;
  const int tid = threadIdx.x;
  const float* Pb = P0 + ((size_t)b * NN + s * 32) * NN;

  // stage 32x512 slab
  for (int f = tid; f < 32 * 128; f += 256) {
    int r = f >> 7, c4 = (f & 127) * 4;
    float4 v = *reinterpret_cast<const float4*>(&Pb[(size_t)r * NN + c4]);
    Pl[r][c4 + 0] = v.x; Pl[r][c4 + 1] = v.y;
    Pl[r][c4 + 2] = v.z; Pl[r][c4 + 3] = v.w;
  }
  cl[tid] = 1.0f; cl[tid + 256] = 1.0f;
  __syncthreads();

  auto row_update = [&]() {  // r_i = 1 / sum_j Pl[i][j] * cl[j]
    const int i = tid & 31, ch = tid >> 5;
    const int j0 = ch * 64;
    float p = 0.0f;
    #pragma unroll 8
    for (int q = 0; q < 64; ++q) p = fmaf(Pl[i][j0 + q], cl[j0 + q], p);
    red[ch][i] = p;
    __syncthreads();
    if (tid < 32) {
      float v = 0.0f;
      #pragma unroll
      for (int q = 0; q < 8; ++q) v += red[q][tid];
      rl[tid] = 1.0f / v;
    }
    __syncthreads();
  };
  row_update();  // r0 = softmax row normalization (folded)

  // flag slot for this block: 64 uints (256 B) apart
  unsigned int* myflag = flags + (size_t)(b * 16 + s) * 64;

  for (int it = 0; it < 60; ++it) {
    // phase A: partial column sums over this block's 32 rows -> publish
    float* pw = pu + (((size_t)(it & 1) * BB + b) * 16 + s) * NN;
    {
      float u0 = 0.0f, u1 = 0.0f;
      #pragma unroll 8
      for (int i2 = 0; i2 < 32; ++i2) {
        const float rv = rl[i2];
        u0 = fmaf(Pl[i2][tid],       rv, u0);
        u1 = fmaf(Pl[i2][tid + 256], rv, u1);
      }
      __hip_atomic_store(&pw[tid],       u0, __ATOMIC_RELAXED, SCOPE_AGENT);
      __hip_atomic_store(&pw[tid + 256], u1, __ATOMIC_RELAXED, SCOPE_AGENT);
    }
    __syncthreads();  // every wave drains vmcnt(0): data is at coherence point

    // arrive: publish own flag (no fence needed — see above)
    if (tid == 0)
      __hip_atomic_store(myflag, (unsigned int)(it + 1),
                         __ATOMIC_RELAXED, SCOPE_AGENT);
    // wait: 16 lanes poll the 16 flags of this batch
    if (tid < 16) {
      const unsigned int* fp = flags + (size_t)(b * 16 + tid) * 64;
      while (__hip_atomic_load(fp, __ATOMIC_RELAXED, SCOPE_AGENT) <
             (unsigned int)(it + 1))
        __builtin_amdgcn_s_sleep(1);
    }
    __syncthreads();

    // phase B: c = 1/colsum ; then local row matvec -> r
    {
      const float* pr = pu + (((size_t)(it & 1) * BB + b) * 16) * NN;
      float t0 = 0.0f, t1 = 0.0f;
      #pragma unroll
      for (int sp = 0; sp < 16; ++sp) {
        t0 += __hip_atomic_load(&pr[sp * NN + tid],       __ATOMIC_RELAXED, SCOPE_AGENT);
        t1 += __hip_atomic_load(&pr[sp * NN + tid + 256], __ATOMIC_RELAXED, SCOPE_AGENT);
      }
      cl[tid] = 1.0f / t0; cl[tid + 256] = 1.0f / t1;
    }
    __syncthreads();
    row_update();
  }

  // final: out = r_i * P0_ij * c_j   (reads LDS only)
  float* Ob = out + ((size_t)b * NN + s * 32) * NN;
  for (int i = 0; i < 32; ++i) {
    const float rv = rl[i];
    Ob[(size_t)i * NN + tid]       = rv * Pl[i][tid]       * cl[tid];
    Ob[(size_t)i * NN + tid + 256] = rv * Pl[i][tid + 256] * cl[tid + 256];
  }
}

// ------------------------------------------------------------- launch ------
extern "C" void kernel_launch(void* const* d_in, const int* in_sizes, int n_in,
                              void* d_out, int out_size, void* d_ws, size_t ws_size,
                              hipStream_t stream)
{
  const float* points = (const float*)d_in[0];
  const float* dist   = (const float*)d_in[1];
  const float* noise  = (const float*)d_in[2];
  const float* Wemb   = (const float*)d_in[3];
  const float* bemb   = (const float*)d_in[4];
  const float* W1 = (const float*)d_in[5]; const float* b1 = (const float*)d_in[6];
  const float* W2 = (const float*)d_in[7]; const float* b2 = (const float*)d_in[8];
  const float* W3 = (const float*)d_in[9]; const float* b3 = (const float*)d_in[10];
  float* out = (float*)d_out;

  char* ws = (char*)d_ws;
  float* xa = (float*)ws;                                // B*N*H f32 = 4 MB
  float* nb = (float*)(ws + (4u << 20));                 // B*N*H f32 = 4 MB
  float* pu = (float*)(ws + (8u << 20));                 // 2*16*16*512 f32 = 1 MB
  unsigned int* flags = (unsigned int*)(ws + (9u << 20)); // 256 slots x 256 B = 64 KB

  hipMemsetAsync(flags, 0, BB * 16 * 64 * sizeof(unsigned int), stream);

  // embed
  embed_kernel<<<(BB * NN * HH) / 256, 256, 0, stream>>>(points, Wemb, bemb, xa);

  // 3 GCN layers: nb = exp(-dist) @ x ; x = relu(nb @ W + b)
  constexpr int GRID_BMM = BB * (NN / BMt) * (HH / BNt);   // 256
  gemm_kernel<0, true,  false, NN, HH, NN><<<GRID_BMM, 256, 0, stream>>>(dist, xa, nullptr, nullptr, nb);
  gemm_kernel<1, false, false, NN, HH, HH><<<GRID_BMM, 256, 0, stream>>>(nb, W1, b1, nullptr, xa);
  gemm_kernel<0, true,  false, NN, HH, NN><<<GRID_BMM, 256, 0, stream>>>(dist, xa, nullptr, nullptr, nb);
  gemm_kernel<1, false, false, NN, HH, HH><<<GRID_BMM, 256, 0, stream>>>(nb, W2, b2, nullptr, xa);
  gemm_kernel<0, true,  false, NN, HH, NN><<<GRID_BMM, 256, 0, stream>>>(dist, xa, nullptr, nullptr, nb);
  gemm_kernel<1, false, false, NN, HH, HH><<<GRID_BMM, 256, 0, stream>>>(nb, W3, b3, nullptr, xa);

  // logits -> y (in d_out), fused mask/tanh/gumbel/T
  constexpr int GRID_LOG = BB * (NN / BMt) * (NN / BNt);   // 1024
  gemm_kernel<2, false, true, NN, NN, HH><<<GRID_LOG, 256, 0, stream>>>(xa, xa, nullptr, noise, out);

  // P0 = exp(y - rowmax)  (in place)
  rowexp_kernel<<<BB * NN, 256, 0, stream>>>(out);

  // Sinkhorn: cooperative launch only for co-residency; sync is hand-rolled.
  const float* P0c = out; float* puP = pu; unsigned int* flagsP = flags; float* outP = out;
  void* args[] = {(void*)&P0c, (void*)&puP, (void*)&flagsP, (void*)&outP};
  hipLaunchCooperativeKernel(reinterpret_cast<void*>(sinkhorn_kernel),
                             dim3(256), dim3(256), args, 0, stream);
}